// Round 11
// baseline (827.333 us; speedup 1.0000x reference)
//
#include <hip/hip_runtime.h>

typedef unsigned int uint;
typedef unsigned long long u64;

#define NPTS   4096
#define KNN    32
#define KSUP   8
#define MAXCQ  352
#define GRID   1024
#define BLKT   256
#define QPBLK  16          // queries per block (4 batches * 4096 / 1024)
#define QBUN   4           // queries per bundle (one per wave)

__device__ __forceinline__ uint fkey(float d) {
    uint u = __float_as_uint(d);
    return u ^ ((u & 0x80000000u) ? 0xFFFFFFFFu : 0x80000000u);
}

// monotonic grid barrier: each block adds 1; pass when bar >= target.
// s_sleep poll + spin cap: a residency failure degrades to wrong answer, not a hang.
__device__ __forceinline__ void grid_barrier(uint* bar, uint target, int tid) {
    __syncthreads();
    if (tid == 0) {
        __threadfence();                       // release: publish our global writes
        atomicAdd(bar, 1u);
        uint spins = 0;
        while (__hip_atomic_load(bar, __ATOMIC_RELAXED, __HIP_MEMORY_SCOPE_AGENT) < target) {
            __builtin_amdgcn_s_sleep(8);
            if (++spins > 2000000u) break;     // ~0.5 s worst-case safety valve
        }
        __threadfence();                       // acquire: see others' global writes
    }
    __syncthreads();
}

__global__ __launch_bounds__(BLKT, 4) void fused_kernel(
        const float* __restrict__ xyz,       // [B*N*3]
        float*       __restrict__ out,       // [B]
        int nout,
        float4*      __restrict__ pts4,      // [B*N]
        float*       __restrict__ covS,      // [B*N][12]
        float*       __restrict__ normals,   // [B*N][3]
        int*         __restrict__ idx8,      // [B*N][8]
        uint*        __restrict__ bar,
        int total)                            // B*N
{
    const int tid = threadIdx.x;
    const int bid = blockIdx.x;
    const int G   = gridDim.x;

    // ================= Phase A: pack + zero out =================
    for (int i = bid * BLKT + tid; i < total; i += G * BLKT) {
        float x = xyz[i*3+0], y = xyz[i*3+1], z = xyz[i*3+2];
        pts4[i] = make_float4(x, y, z, x*x + y*y + z*z);
    }
    if (bid == 0 && tid < nout) out[tid] = 0.0f;
    grid_barrier(bar, 1u * G, tid);

    // ================= Phase B: kNN + covariance =================
    {
        const int wv   = tid >> 6;     // wave slot 0..3 == bundle query slot
        const int lane = tid & 63;

        __shared__ u64  cand[QBUN][MAXCQ];   // 11 KB
        __shared__ uint ccnt[QBUN];
        __shared__ int  sel[QBUN][KNN];

        const int q0blk = bid * QPBLK;       // block never crosses a batch (4096 % 16 == 0)
        const int b     = q0blk >> 12;
        const float4* P = pts4 + (size_t)b * NPTS;

        for (int bun = 0; bun < QPBLK; bun += QBUN) {
            const int nq0 = (q0blk & (NPTS - 1)) + bun;    // within-batch base query

            float qx[QBUN], qy[QBUN], qz[QBUN], qs[QBUN], t0[QBUN];
            #pragma unroll
            for (int j = 0; j < QBUN; ++j) {
                float4 q = P[nq0 + j];
                qx[j] = q.x; qy[j] = q.y; qz[j] = q.z; qs[j] = q.w;
                // analytic 32-NN distance^2 bound for N(0,1)^3 (E[cnt]~70)
                t0[j] = 0.1606f * __expf(q.w * (1.0f / 3.0f));
            }
            if (tid < QBUN) ccnt[tid] = 0;
            __syncthreads();

            // one pass over all points, 4 queries amortized per load
            #pragma unroll 2
            for (int it = 0; it < NPTS / BLKT; ++it) {
                const int m = tid + it * BLKT;
                float4 p = P[m];
                #pragma unroll
                for (int j = 0; j < QBUN; ++j) {
                    float d = qs[j] + p.w - 2.0f * (qx[j]*p.x + qy[j]*p.y + qz[j]*p.z);
                    if (d < t0[j]) {
                        uint pos = atomicAdd(&ccnt[j], 1u);
                        if (pos < MAXCQ) cand[j][pos] = ((u64)fkey(d) << 12) | (uint)m;
                    }
                }
            }
            __syncthreads();

            // each wave selects for its own query
            const uint cnt = ccnt[wv];
            const int  pid = b * NPTS + nq0 + wv;

            if (cnt >= KNN && cnt <= MAXCQ) {
                // exact stable rank selection on packed (key,idx)
                const int M = (int)cnt;
                for (int i = lane; i < ((M + 63) & ~63); i += 64) {
                    u64 my = (i < M) ? cand[wv][i] : ~0ull;
                    int r = 0;
                    for (int jj = 0; jj < M; ++jj) r += (cand[wv][jj] < my) ? 1 : 0;
                    if (i < M && r < KNN) sel[wv][r] = (int)(my & 0xFFFull);
                }
            } else {
                // guaranteed-exact terminal: 32 wave-parallel min-extractions (rare)
                u64 last = 0;
                for (int r = 0; r < KNN; ++r) {
                    u64 best = ~0ull;
                    for (int k0 = 0; k0 < NPTS; k0 += 64) {
                        const int k = k0 + lane;
                        float4 p = P[k];
                        float d = qs[wv] + p.w - 2.0f * (qx[wv]*p.x + qy[wv]*p.y + qz[wv]*p.z);
                        u64 pk = ((u64)fkey(d) << 12) | (uint)k;
                        if (pk > last && pk < best) best = pk;
                    }
                    #pragma unroll
                    for (int off = 32; off; off >>= 1) {
                        u64 o = __shfl_xor(best, off, 64);
                        best = (o < best) ? o : best;
                    }
                    if (lane == 0) sel[wv][r] = (int)(best & 0xFFFull);
                    last = best;
                }
            }

            // covariance: lanes 0..31 of the owning wave (reads own wave's sel)
            if (lane < 32) {
                const int jn = sel[wv][lane];
                float4 pj = P[jn];
                float p0 = pj.x, p1 = pj.y, p2 = pj.z;

                float s0 = p0, s1 = p1, s2 = p2;
                #pragma unroll
                for (int ml = 1; ml < 32; ml <<= 1) {
                    s0 += __shfl_xor(s0, ml, 32);
                    s1 += __shfl_xor(s1, ml, 32);
                    s2 += __shfl_xor(s2, ml, 32);
                }
                const float c0 = s0 * (1.0f/32.0f), c1 = s1 * (1.0f/32.0f), c2 = s2 * (1.0f/32.0f);
                const float X0 = p0 - c0, X1 = p1 - c1, X2 = p2 - c2;
                float xx = X0*X0, xy = X0*X1, xz = X0*X2, yy = X1*X1, yz = X1*X2, zz = X2*X2;
                #pragma unroll
                for (int ml = 1; ml < 32; ml <<= 1) {
                    xx += __shfl_xor(xx, ml, 32);
                    xy += __shfl_xor(xy, ml, 32);
                    xz += __shfl_xor(xz, ml, 32);
                    yy += __shfl_xor(yy, ml, 32);
                    yz += __shfl_xor(yz, ml, 32);
                    zz += __shfl_xor(zz, ml, 32);
                }
                if (lane == 0) {
                    float4* o = (float4*)(covS + (size_t)pid * 12);
                    o[0] = make_float4(xx, xy, xz, yy);
                    o[1] = make_float4(yz, zz, s0 - 32.0f*qx[wv], s1 - 32.0f*qy[wv]);
                    o[2] = make_float4(s2 - 32.0f*qz[wv], 0.0f, 0.0f, 0.0f);
                }
            }
            if (lane < KSUP) idx8[(size_t)pid*KSUP + lane] = sel[wv][lane];
            __syncthreads();   // protect cand/ccnt reuse in next bundle
        }
    }
    grid_barrier(bar, 2u * G, tid);

    // ================= Phase C: 3x3 eigensolve -> oriented normal =================
    for (int pid = bid * BLKT + tid; pid < total; pid += G * BLKT) {
        const float4* c4 = (const float4*)(covS + (size_t)pid * 12);
        const float4 a = c4[0], bb = c4[1], cc = c4[2];

        double A00 = a.x, A01 = a.y, A02 = a.z, A11 = a.w, A12 = bb.x, A22 = bb.y;
        const float S0 = bb.z, S1 = bb.w, S2 = cc.x;
        double V00=1, V01=0, V02=0, V10=0, V11=1, V12=0, V20=0, V21=0, V22=1;

        #pragma unroll
        for (int sweep = 0; sweep < 5; ++sweep) {
            {
                double apq = A01;
                if (fabs(apq) > 1e-300) {
                    double th = (A11 - A00) / (2.0*apq);
                    double t  = (th >= 0.0 ? 1.0 : -1.0) / (fabs(th) + sqrt(th*th + 1.0));
                    double c  = 1.0/sqrt(t*t + 1.0), s = t*c;
                    double a00 = c*c*A00 - 2.0*s*c*A01 + s*s*A11;
                    double a11 = s*s*A00 + 2.0*s*c*A01 + c*c*A11;
                    double a02 = c*A02 - s*A12;
                    double a12 = s*A02 + c*A12;
                    A00 = a00; A11 = a11; A01 = 0.0; A02 = a02; A12 = a12;
                    double v0, v1;
                    v0 = V00; v1 = V01; V00 = c*v0 - s*v1; V01 = s*v0 + c*v1;
                    v0 = V10; v1 = V11; V10 = c*v0 - s*v1; V11 = s*v0 + c*v1;
                    v0 = V20; v1 = V21; V20 = c*v0 - s*v1; V21 = s*v0 + c*v1;
                }
            }
            {
                double apq = A02;
                if (fabs(apq) > 1e-300) {
                    double th = (A22 - A00) / (2.0*apq);
                    double t  = (th >= 0.0 ? 1.0 : -1.0) / (fabs(th) + sqrt(th*th + 1.0));
                    double c  = 1.0/sqrt(t*t + 1.0), s = t*c;
                    double a00 = c*c*A00 - 2.0*s*c*A02 + s*s*A22;
                    double a22 = s*s*A00 + 2.0*s*c*A02 + c*c*A22;
                    double a01 = c*A01 - s*A12;
                    double a12 = s*A01 + c*A12;
                    A00 = a00; A22 = a22; A02 = 0.0; A01 = a01; A12 = a12;
                    double v0, v1;
                    v0 = V00; v1 = V02; V00 = c*v0 - s*v1; V02 = s*v0 + c*v1;
                    v0 = V10; v1 = V12; V10 = c*v0 - s*v1; V12 = s*v0 + c*v1;
                    v0 = V20; v1 = V22; V20 = c*v0 - s*v1; V22 = s*v0 + c*v1;
                }
            }
            {
                double apq = A12;
                if (fabs(apq) > 1e-300) {
                    double th = (A22 - A11) / (2.0*apq);
                    double t  = (th >= 0.0 ? 1.0 : -1.0) / (fabs(th) + sqrt(th*th + 1.0));
                    double c  = 1.0/sqrt(t*t + 1.0), s = t*c;
                    double a11 = c*c*A11 - 2.0*s*c*A12 + s*s*A22;
                    double a22 = s*s*A11 + 2.0*s*c*A12 + c*c*A22;
                    double a01 = c*A01 - s*A02;
                    double a02 = s*A01 + c*A02;
                    A11 = a11; A22 = a22; A12 = 0.0; A01 = a01; A02 = a02;
                    double v0, v1;
                    v0 = V01; v1 = V02; V01 = c*v0 - s*v1; V02 = s*v0 + c*v1;
                    v0 = V11; v1 = V12; V11 = c*v0 - s*v1; V12 = s*v0 + c*v1;
                    v0 = V21; v1 = V22; V21 = c*v0 - s*v1; V22 = s*v0 + c*v1;
                }
            }
        }

        double e0 = A00, e1 = A11, e2 = A22;
        double v0, v1, v2;
        if (e0 <= e1 && e0 <= e2)      { v0 = V00; v1 = V10; v2 = V20; }
        else if (e1 <= e0 && e1 <= e2) { v0 = V01; v1 = V11; v2 = V21; }
        else                           { v0 = V02; v1 = V12; v2 = V22; }
        double nrm = sqrt(v0*v0 + v1*v1 + v2*v2);
        if (nrm > 0.0) { v0 /= nrm; v1 /= nrm; v2 /= nrm; }

        float f0 = (float)v0, f1 = (float)v1, f2 = (float)v2;
        float proj = f0*S0 + f1*S1 + f2*S2;
        if (proj < 0.0f) { f0 = -f0; f1 = -f1; f2 = -f2; }
        normals[(size_t)pid*3+0] = f0;
        normals[(size_t)pid*3+1] = f1;
        normals[(size_t)pid*3+2] = f2;
    }
    grid_barrier(bar, 3u * G, tid);

    // ================= Phase D: penalty std + batch mean =================
    {
        const int pid = bid * BLKT + tid;
        float v = 0.0f;
        if (pid < total) {
            const int bb2 = pid >> 12;
            const int* my = idx8 + (size_t)pid * KSUP;
            const float* nb_base = normals + (size_t)bb2 * NPTS * 3;

            const int i0 = my[0];
            const float a0 = nb_base[i0*3+0], a1 = nb_base[i0*3+1], a2 = nb_base[i0*3+2];
            const float na = fmaxf(sqrtf(a0*a0 + a1*a1 + a2*a2), 1e-6f);

            float p[KSUP];
            float sum = 0.0f;
            #pragma unroll
            for (int k = 0; k < KSUP; ++k) {
                int ik = my[k];
                float b0 = nb_base[ik*3+0], b1 = nb_base[ik*3+1], b2 = nb_base[ik*3+2];
                float nbn = fmaxf(sqrtf(b0*b0 + b1*b1 + b2*b2), 1e-6f);
                float cosv = (a0*b0 + a1*b1 + a2*b2) / (na * nbn);
                p[k] = 1.0f - cosv;
                sum += p[k];
            }
            const float mean = sum * (1.0f / 8.0f);
            float var = 0.0f;
            #pragma unroll
            for (int k = 0; k < KSUP; ++k) { float dv = p[k] - mean; var += dv * dv; }
            v = sqrtf(var * (1.0f / 7.0f)) * (1.0f / 4096.0f);
        }
        #pragma unroll
        for (int ml = 1; ml < 64; ml <<= 1) v += __shfl_xor(v, ml, 64);
        if ((tid & 63) == 0 && pid < total) {
            atomicAdd(&out[pid >> 12], v);
        }
    }
}

extern "C" void kernel_launch(void* const* d_in, const int* in_sizes, int n_in,
                              void* d_out, int out_size, void* d_ws, size_t ws_size,
                              hipStream_t stream) {
    const float* xyz = (const float*)d_in[0];
    float* out = (float*)d_out;

    const int B = in_sizes[0] / (NPTS * 3);   // 4
    const int total = B * NPTS;

    char* ws = (char*)d_ws;
    uint*   bar     = (uint*)ws;                         ws += 256;
    float4* pts4    = (float4*)ws;                       ws += (size_t)total * sizeof(float4);
    float*  covS    = (float*)ws;                        ws += (size_t)total * 12 * sizeof(float);
    float*  normals = (float*)ws;                        ws += (size_t)total * 3 * sizeof(float);
    int*    idx8    = (int*)ws;

    hipMemsetAsync(bar, 0, 256, stream);
    hipLaunchKernelGGL(fused_kernel, dim3(GRID), dim3(BLKT), 0, stream,
                       xyz, out, out_size, pts4, covS, normals, idx8, bar, total);
}

// Round 14
// 423.344 us; speedup vs baseline: 1.9543x; 1.9543x over previous
//
#include <hip/hip_runtime.h>

typedef unsigned int uint;
typedef unsigned long long u64;

#define NPTS   4096
#define KNN    32
#define KSUP   8
#define MAXCQ  256
#define GRID   1024
#define BLKT   256
#define QPBLK  16          // queries per block
#define QBUN   8           // queries per shared scan pass

__device__ __forceinline__ uint fkey(float d) {
    uint u = __float_as_uint(d);
    return u ^ ((u & 0x80000000u) ? 0xFFFFFFFFu : 0x80000000u);
}
__device__ __forceinline__ uint lanebits(u64 mask) {
    return __builtin_amdgcn_mbcnt_hi((uint)(mask >> 32),
           __builtin_amdgcn_mbcnt_lo((uint)mask, 0u));
}

// monotonic grid barrier: each block adds 1; pass when bar >= target.
__device__ __forceinline__ void grid_barrier(uint* bar, uint target, int tid) {
    __syncthreads();
    if (tid == 0) {
        __threadfence();
        atomicAdd(bar, 1u);
        uint spins = 0;
        while (__hip_atomic_load(bar, __ATOMIC_RELAXED, __HIP_MEMORY_SCOPE_AGENT) < target) {
            __builtin_amdgcn_s_sleep(2);
            if (++spins > 4000000u) break;     // safety valve
        }
        __threadfence();
    }
    __syncthreads();
}

__global__ __launch_bounds__(BLKT, 4) void fused_kernel(
        const float* __restrict__ xyz,       // [B*N*3]
        float*       __restrict__ out,       // [B]
        int nout,
        float4*      __restrict__ pts4,      // [B*N]
        float*       __restrict__ normals,   // [B*N][3]
        int*         __restrict__ idx8,      // [B*N][8]
        uint*        __restrict__ bar,
        int total)                            // B*N
{
    const int tid = threadIdx.x;
    const int bid = blockIdx.x;
    const int G   = gridDim.x;

    // ================= Phase A: pack + zero out =================
    for (int i = bid * BLKT + tid; i < total; i += G * BLKT) {
        float x = xyz[i*3+0], y = xyz[i*3+1], z = xyz[i*3+2];
        pts4[i] = make_float4(x, y, z, x*x + y*y + z*z);
    }
    if (bid == 0 && tid < nout) out[tid] = 0.0f;
    grid_barrier(bar, 1u * G, tid);

    // ================= Phase B: kNN + cov + eig =================
    {
        const int wv   = tid >> 6;     // wave 0..3
        const int lane = tid & 63;

        __shared__ u64   cand[QBUN][MAXCQ];    // 16 KB
        __shared__ uint  ccnt[QBUN];
        __shared__ int   sel[QPBLK][KNN];      // 2 KB
        __shared__ float covsm[QPBLK][12];     // cov6 + S3

        const int q0blk = bid * QPBLK;         // block never crosses a batch
        const int b     = q0blk >> 12;
        const int nbase = q0blk & (NPTS - 1);
        const float4* P = pts4 + (size_t)b * NPTS;

        for (int half = 0; half < 2; ++half) {
            const int nq0 = nbase + half * QBUN;

            float qx[QBUN], qy[QBUN], qz[QBUN], qs[QBUN], tt[QBUN];
            #pragma unroll
            for (int j = 0; j < QBUN; ++j) {
                float4 q = P[nq0 + j];
                qx[j] = q.x; qy[j] = q.y; qz[j] = q.z; qs[j] = q.w;
                tt[j] = 0.1606f * __expf(q.w * (1.0f / 3.0f));  // analytic 32-NN bound
            }
            if (tid < QBUN) ccnt[tid] = 0;
            __syncthreads();

            // ---- shared scan: 8 queries amortized per point-load ----
            #pragma unroll 2
            for (int it = 0; it < NPTS / BLKT; ++it) {
                const int m = tid + it * BLKT;
                float4 p = P[m];
                #pragma unroll
                for (int j = 0; j < QBUN; ++j) {
                    float d = qs[j] + p.w - 2.0f * (qx[j]*p.x + qy[j]*p.y + qz[j]*p.z);
                    if (d < tt[j]) {
                        uint pos = atomicAdd(&ccnt[j], 1u);
                        if (pos < MAXCQ) cand[j][pos] = ((u64)fkey(d) << 12) | (uint)m;
                    }
                }
            }
            __syncthreads();

            // ---- per-wave: 2 queries each (j = wv, wv+4) ----
            for (int rep = 0; rep < 2; ++rep) {
                const int j    = wv + rep * 4;
                const int nq   = nq0 + j;
                const int qloc = half * QBUN + j;
                const int pid  = b * NPTS + nq;

                // per-query scalars (no runtime-indexed register arrays)
                const float4 q = P[nq];
                const float ax = q.x, ay = q.y, az = q.z, as_ = q.w;

                uint cnt = ccnt[j];
                float t = 0.1606f * __expf(as_ * (1.0f / 3.0f));

                // adaptive wave-private rescan when out of [KNN, MAXCQ]
                for (int att = 0; (cnt < KNN || cnt > MAXCQ) && att < 12; ++att) {
                    t = (cnt < KNN) ? t * 2.2f : t * 0.5f;
                    cnt = 0;
                    for (int k0 = 0; k0 < NPTS; k0 += 64) {
                        const int k = k0 + lane;
                        float4 p = P[k];
                        float d = as_ + p.w - 2.0f * (ax*p.x + ay*p.y + az*p.z);
                        bool pred = d < t;
                        u64 mask = __ballot(pred);
                        if (pred) {
                            uint pos = cnt + lanebits(mask);
                            if (pos < MAXCQ) cand[j][pos] = ((u64)fkey(d) << 12) | (uint)k;
                        }
                        cnt += (uint)__popcll(mask);
                    }
                }

                if (cnt >= KNN && cnt <= MAXCQ) {
                    // exact stable rank selection on packed (key,idx)
                    const int M = (int)cnt;
                    for (int i = lane; i < ((M + 63) & ~63); i += 64) {
                        u64 my = (i < M) ? cand[j][i] : ~0ull;
                        int r = 0;
                        for (int jj = 0; jj < M; ++jj) r += (cand[j][jj] < my) ? 1 : 0;
                        if (i < M && r < KNN) sel[qloc][r] = (int)(my & 0xFFFull);
                    }
                } else {
                    // guaranteed-exact backstop (unreachable): 32 min-extractions
                    u64 last = 0;
                    for (int r = 0; r < KNN; ++r) {
                        u64 best = ~0ull;
                        for (int k0 = 0; k0 < NPTS; k0 += 64) {
                            const int k = k0 + lane;
                            float4 p = P[k];
                            float d = as_ + p.w - 2.0f * (ax*p.x + ay*p.y + az*p.z);
                            u64 pk = ((u64)fkey(d) << 12) | (uint)k;
                            if (pk > last && pk < best) best = pk;
                        }
                        #pragma unroll
                        for (int off = 32; off; off >>= 1) {
                            u64 o = __shfl_xor(best, off, 64);
                            best = (o < best) ? o : best;
                        }
                        if (lane == 0) sel[qloc][r] = (int)(best & 0xFFFull);
                        last = best;
                    }
                }

                // covariance: lanes 0..31 (same wave wrote sel[qloc])
                if (lane < 32) {
                    const int jn = sel[qloc][lane];
                    float4 pj = P[jn];
                    float p0 = pj.x, p1 = pj.y, p2 = pj.z;

                    float s0 = p0, s1 = p1, s2 = p2;
                    #pragma unroll
                    for (int ml = 1; ml < 32; ml <<= 1) {
                        s0 += __shfl_xor(s0, ml, 32);
                        s1 += __shfl_xor(s1, ml, 32);
                        s2 += __shfl_xor(s2, ml, 32);
                    }
                    const float c0 = s0*(1.0f/32.0f), c1 = s1*(1.0f/32.0f), c2 = s2*(1.0f/32.0f);
                    const float X0 = p0 - c0, X1 = p1 - c1, X2 = p2 - c2;
                    float xx = X0*X0, xy = X0*X1, xz = X0*X2, yy = X1*X1, yz = X1*X2, zz = X2*X2;
                    #pragma unroll
                    for (int ml = 1; ml < 32; ml <<= 1) {
                        xx += __shfl_xor(xx, ml, 32);
                        xy += __shfl_xor(xy, ml, 32);
                        xz += __shfl_xor(xz, ml, 32);
                        yy += __shfl_xor(yy, ml, 32);
                        yz += __shfl_xor(yz, ml, 32);
                        zz += __shfl_xor(zz, ml, 32);
                    }
                    if (lane == 0) {
                        covsm[qloc][0] = xx; covsm[qloc][1] = xy; covsm[qloc][2] = xz;
                        covsm[qloc][3] = yy; covsm[qloc][4] = yz; covsm[qloc][5] = zz;
                        covsm[qloc][6] = s0 - 32.0f*ax;
                        covsm[qloc][7] = s1 - 32.0f*ay;
                        covsm[qloc][8] = s2 - 32.0f*az;
                    }
                }
                if (lane < KSUP) idx8[(size_t)pid*KSUP + lane] = sel[qloc][lane];
            }
            __syncthreads();   // protect cand/ccnt before next half
        }

        // ---- eig for the block's 16 queries (tid 0..15) ----
        if (tid < QPBLK) {
            double A00 = covsm[tid][0], A01 = covsm[tid][1], A02 = covsm[tid][2];
            double A11 = covsm[tid][3], A12 = covsm[tid][4], A22 = covsm[tid][5];
            const float S0 = covsm[tid][6], S1 = covsm[tid][7], S2 = covsm[tid][8];
            double V00=1, V01=0, V02=0, V10=0, V11=1, V12=0, V20=0, V21=0, V22=1;

            #pragma unroll
            for (int sweep = 0; sweep < 5; ++sweep) {
                {
                    double apq = A01;
                    if (fabs(apq) > 1e-300) {
                        double th = (A11 - A00) / (2.0*apq);
                        double t2 = (th >= 0.0 ? 1.0 : -1.0) / (fabs(th) + sqrt(th*th + 1.0));
                        double c  = 1.0/sqrt(t2*t2 + 1.0), s = t2*c;
                        double a00 = c*c*A00 - 2.0*s*c*A01 + s*s*A11;
                        double a11 = s*s*A00 + 2.0*s*c*A01 + c*c*A11;
                        double a02 = c*A02 - s*A12;
                        double a12 = s*A02 + c*A12;
                        A00 = a00; A11 = a11; A01 = 0.0; A02 = a02; A12 = a12;
                        double v0, v1;
                        v0 = V00; v1 = V01; V00 = c*v0 - s*v1; V01 = s*v0 + c*v1;
                        v0 = V10; v1 = V11; V10 = c*v0 - s*v1; V11 = s*v0 + c*v1;
                        v0 = V20; v1 = V21; V20 = c*v0 - s*v1; V21 = s*v0 + c*v1;
                    }
                }
                {
                    double apq = A02;
                    if (fabs(apq) > 1e-300) {
                        double th = (A22 - A00) / (2.0*apq);
                        double t2 = (th >= 0.0 ? 1.0 : -1.0) / (fabs(th) + sqrt(th*th + 1.0));
                        double c  = 1.0/sqrt(t2*t2 + 1.0), s = t2*c;
                        double a00 = c*c*A00 - 2.0*s*c*A02 + s*s*A22;
                        double a22 = s*s*A00 + 2.0*s*c*A02 + c*c*A22;
                        double a01 = c*A01 - s*A12;
                        double a12 = s*A01 + c*A12;
                        A00 = a00; A22 = a22; A02 = 0.0; A01 = a01; A12 = a12;
                        double v0, v1;
                        v0 = V00; v1 = V02; V00 = c*v0 - s*v1; V02 = s*v0 + c*v1;
                        v0 = V10; v1 = V12; V10 = c*v0 - s*v1; V12 = s*v0 + c*v1;
                        v0 = V20; v1 = V22; V20 = c*v0 - s*v1; V22 = s*v0 + c*v1;
                    }
                }
                {
                    double apq = A12;
                    if (fabs(apq) > 1e-300) {
                        double th = (A22 - A11) / (2.0*apq);
                        double t2 = (th >= 0.0 ? 1.0 : -1.0) / (fabs(th) + sqrt(th*th + 1.0));
                        double c  = 1.0/sqrt(t2*t2 + 1.0), s = t2*c;
                        double a11 = c*c*A11 - 2.0*s*c*A12 + s*s*A22;
                        double a22 = s*s*A11 + 2.0*s*c*A12 + c*c*A22;
                        double a01 = c*A01 - s*A02;
                        double a02 = s*A01 + c*A02;
                        A11 = a11; A22 = a22; A12 = 0.0; A01 = a01; A02 = a02;
                        double v0, v1;
                        v0 = V01; v1 = V02; V01 = c*v0 - s*v1; V02 = s*v0 + c*v1;
                        v0 = V11; v1 = V12; V11 = c*v0 - s*v1; V12 = s*v0 + c*v1;
                        v0 = V21; v1 = V22; V21 = c*v0 - s*v1; V22 = s*v0 + c*v1;
                    }
                }
            }

            double e0 = A00, e1 = A11, e2 = A22;
            double v0, v1, v2;
            if (e0 <= e1 && e0 <= e2)      { v0 = V00; v1 = V10; v2 = V20; }
            else if (e1 <= e0 && e1 <= e2) { v0 = V01; v1 = V11; v2 = V21; }
            else                           { v0 = V02; v1 = V12; v2 = V22; }
            double nrm = sqrt(v0*v0 + v1*v1 + v2*v2);
            if (nrm > 0.0) { v0 /= nrm; v1 /= nrm; v2 /= nrm; }

            float f0 = (float)v0, f1 = (float)v1, f2 = (float)v2;
            float proj = f0*S0 + f1*S1 + f2*S2;
            if (proj < 0.0f) { f0 = -f0; f1 = -f1; f2 = -f2; }
            const int pid = b * NPTS + nbase + tid;
            normals[(size_t)pid*3+0] = f0;
            normals[(size_t)pid*3+1] = f1;
            normals[(size_t)pid*3+2] = f2;
        }
    }
    grid_barrier(bar, 2u * G, tid);

    // ================= Phase D: penalty std + batch mean =================
    {
        const int pid = bid * BLKT + tid;
        float v = 0.0f;
        if (pid < total) {
            const int bb2 = pid >> 12;
            const int* my = idx8 + (size_t)pid * KSUP;
            const float* nb_base = normals + (size_t)bb2 * NPTS * 3;

            const int i0 = my[0];
            const float a0 = nb_base[i0*3+0], a1 = nb_base[i0*3+1], a2 = nb_base[i0*3+2];
            const float na = fmaxf(sqrtf(a0*a0 + a1*a1 + a2*a2), 1e-6f);

            float p[KSUP];
            float sum = 0.0f;
            #pragma unroll
            for (int k = 0; k < KSUP; ++k) {
                int ik = my[k];
                float b0 = nb_base[ik*3+0], b1 = nb_base[ik*3+1], b2 = nb_base[ik*3+2];
                float nbn = fmaxf(sqrtf(b0*b0 + b1*b1 + b2*b2), 1e-6f);
                float cosv = (a0*b0 + a1*b1 + a2*b2) / (na * nbn);
                p[k] = 1.0f - cosv;
                sum += p[k];
            }
            const float mean = sum * (1.0f / 8.0f);
            float var = 0.0f;
            #pragma unroll
            for (int k = 0; k < KSUP; ++k) { float dv = p[k] - mean; var += dv * dv; }
            v = sqrtf(var * (1.0f / 7.0f)) * (1.0f / 4096.0f);
        }
        #pragma unroll
        for (int ml = 1; ml < 64; ml <<= 1) v += __shfl_xor(v, ml, 64);
        if ((tid & 63) == 0 && pid < total) {
            atomicAdd(&out[pid >> 12], v);
        }
    }
}

extern "C" void kernel_launch(void* const* d_in, const int* in_sizes, int n_in,
                              void* d_out, int out_size, void* d_ws, size_t ws_size,
                              hipStream_t stream) {
    const float* xyz = (const float*)d_in[0];
    float* out = (float*)d_out;

    const int B = in_sizes[0] / (NPTS * 3);   // 4
    const int total = B * NPTS;

    char* ws = (char*)d_ws;
    uint*   bar     = (uint*)ws;                         ws += 256;
    float4* pts4    = (float4*)ws;                       ws += (size_t)total * sizeof(float4);
    float*  normals = (float*)ws;                        ws += (size_t)total * 3 * sizeof(float);
    int*    idx8    = (int*)ws;

    hipMemsetAsync(bar, 0, 256, stream);
    hipLaunchKernelGGL(fused_kernel, dim3(GRID), dim3(BLKT), 0, stream,
                       xyz, out, out_size, pts4, normals, idx8, bar, total);
}